// Round 5
// baseline (493.313 us; speedup 1.0000x reference)
//
#include <hip/hip_runtime.h>
#include <stdint.h>
#include <stddef.h>

// Problem constants
#define BB 4
#define CC 256
#define NH 8
#define DH 32
#define NN 2304      // 48*48
#define O3 768
#define HID 256
#define QK_SCALE 0.17677669529663687f  // 32^-0.5
#define LOG2E 1.44269504f

typedef __attribute__((ext_vector_type(8))) short short8;
typedef __attribute__((ext_vector_type(4))) float float4v;

__device__ __forceinline__ unsigned short f2bf(float f) {
    union { float f; uint32_t u; } v; v.f = f;
    uint32_t u = v.u;
    return (unsigned short)((u + 0x7FFFu + ((u >> 16) & 1u)) >> 16);   // RNE
}
__device__ __forceinline__ float bf2f(unsigned short s) {
    union { uint32_t u; float f; } v; v.u = ((uint32_t)s) << 16;
    return v.f;
}
__device__ __forceinline__ float bits2f(uint32_t u) {
    union { uint32_t u; float f; } v; v.u = u;
    return v.f;
}

// ---------------------------------------------------------------------------
// K0: prep = transpose-cast x -> xT bf16  (blocks 0..2303)
//          + cast w_qkv hi/lo, w_out      (blocks 2304..3071)
// ---------------------------------------------------------------------------
__global__ __launch_bounds__(256) void prep_kernel(const float* __restrict__ x,
                                                   const float* __restrict__ wqkv,
                                                   const float* __restrict__ wout,
                                                   unsigned short* __restrict__ xT,
                                                   unsigned short* __restrict__ whi,
                                                   unsigned short* __restrict__ wlo,
                                                   unsigned short* __restrict__ wob) {
    const int bid = blockIdx.x;
    const int t = threadIdx.x;
    if (bid < 2304) {      // transpose 32x32 tile of x
        const int n0 = (bid % 72) * 32, c0 = ((bid / 72) % 8) * 32, b = bid / 576;
        __shared__ float ls[32][33];
        {
            int c = t >> 3, nc = (t & 7) * 4;
            float4 v4 = *(const float4*)(x + ((size_t)b * CC + c0 + c) * NN + n0 + nc);
            ls[c][nc] = v4.x; ls[c][nc + 1] = v4.y; ls[c][nc + 2] = v4.z; ls[c][nc + 3] = v4.w;
        }
        __syncthreads();
        {
            int n = t >> 3, cl = (t & 7) * 4;
            uint32_t p0 = (uint32_t)f2bf(ls[cl + 0][n]) | ((uint32_t)f2bf(ls[cl + 1][n]) << 16);
            uint32_t p1 = (uint32_t)f2bf(ls[cl + 2][n]) | ((uint32_t)f2bf(ls[cl + 3][n]) << 16);
            uint32_t* dst = (uint32_t*)(xT + ((size_t)b * NN + n0 + n) * CC + c0 + cl);
            dst[0] = p0; dst[1] = p1;
        }
    } else {               // weight casts
        int i = (bid - 2304) * 256 + t;
        float wv = wqkv[i];
        unsigned short hi = f2bf(wv);
        whi[i] = hi;
        wlo[i] = f2bf(wv - bf2f(hi));
        if (i < HID * HID) wob[i] = f2bf(wout[i]);
    }
}

// ---------------------------------------------------------------------------
// K1: fused QKV projection, bf16 MFMA, writes q/k/v directly in final layouts.
//   q,k bf16 [b][h][n][32] (q scaled by QK_SCALE*LOG2E), v bf16 [b][h][32][n]
// ---------------------------------------------------------------------------
__global__ __launch_bounds__(256) void qkv_gemm_bf16(const unsigned short* __restrict__ xT,
                                                     const unsigned short* __restrict__ whi,
                                                     const unsigned short* __restrict__ wlo,
                                                     unsigned short* __restrict__ q,
                                                     unsigned short* __restrict__ k,
                                                     unsigned short* __restrict__ v) {
    const int og = blockIdx.x;
    const int n0 = blockIdx.y * 64;
    const int b  = blockIdx.z;
    const int t = threadIdx.x;
    const int w = t >> 6, lane = t & 63, l15 = lane & 15, quad = lane >> 4;
    const unsigned short* xb = xT + (size_t)b * NN * CC;

    float4v acc[4] = {{0.f,0.f,0.f,0.f},{0.f,0.f,0.f,0.f},
                      {0.f,0.f,0.f,0.f},{0.f,0.f,0.f,0.f}};

    if (og < 8) {   // ---- qk mode: A = xT rows n, B = w rows o ----
        const int o0 = og * 64;
        const unsigned short* ap = xb + (size_t)(n0 + w * 16 + l15) * CC + quad * 8;
        #pragma unroll
        for (int c0 = 0; c0 < CC; c0 += 32) {
            short8 af = *(const short8*)(ap + c0);
            #pragma unroll
            for (int jj = 0; jj < 4; ++jj) {
                const size_t wo = (size_t)(o0 + jj * 16 + l15) * CC + c0 + quad * 8;
                short8 bh = *(const short8*)(whi + wo);
                short8 bl = *(const short8*)(wlo + wo);
                acc[jj] = __builtin_amdgcn_mfma_f32_16x16x32_bf16(af, bh, acc[jj], 0, 0, 0);
                acc[jj] = __builtin_amdgcn_mfma_f32_16x16x32_bf16(af, bl, acc[jj], 0, 0, 0);
            }
        }
        #pragma unroll
        for (int jj = 0; jj < 4; ++jj) {
            const int o = o0 + jj * 16 + l15;
            const int which = o >> 8;            // 0=q 1=k
            const int h = (o >> 5) & 7, d = o & 31;
            unsigned short* dst = which ? k : q;
            const float sc = which ? 1.0f : QK_SCALE * LOG2E;
            #pragma unroll
            for (int r = 0; r < 4; ++r) {
                const int n = n0 + w * 16 + quad * 4 + r;
                dst[(((size_t)b * NH + h) * NN + n) * DH + d] = f2bf(acc[jj][r] * sc);
            }
        }
    } else {        // ---- v mode: A = w rows o, B = xT rows n ----
        const int o0 = 512 + (og - 8) * 64;
        const size_t wr = (size_t)(o0 + w * 16 + l15) * CC + quad * 8;
        #pragma unroll
        for (int c0 = 0; c0 < CC; c0 += 32) {
            short8 ah = *(const short8*)(whi + wr + c0);
            short8 al = *(const short8*)(wlo + wr + c0);
            #pragma unroll
            for (int jj = 0; jj < 4; ++jj) {
                short8 bf = *(const short8*)(xb + (size_t)(n0 + jj * 16 + l15) * CC + c0 + quad * 8);
                acc[jj] = __builtin_amdgcn_mfma_f32_16x16x32_bf16(ah, bf, acc[jj], 0, 0, 0);
                acc[jj] = __builtin_amdgcn_mfma_f32_16x16x32_bf16(al, bf, acc[jj], 0, 0, 0);
            }
        }
        #pragma unroll
        for (int r = 0; r < 4; ++r) {
            const int o = o0 + w * 16 + quad * 4 + r;
            const int h = (o >> 5) & 7, d = o & 31;
            #pragma unroll
            for (int jj = 0; jj < 4; ++jj) {
                const int n = n0 + jj * 16 + l15;
                v[(((size_t)b * NH + h) * DH + d) * NN + n] = f2bf(acc[jj][r]);
            }
        }
    }
}

// ---------------------------------------------------------------------------
// K2: fused attention v4. QBLK=32: each wave computes TWO 16-row q-sub-tiles
// against the SAME K/V tile -> K/V L2 traffic halved, 16 MFMAs per 16 loads.
// Grid (NN/32=72, NH=8) = 576 blocks of 4 waves (wave=batch), 2.25 blocks/CU
// supply; __launch_bounds__(256,3) caps VGPR so >=3 blocks/CU fit -> entire
// grid co-resident, no serialized block rounds (the round-4 tail).
// Bias shared across the 4 batch-waves in LDS as bf16 (v2-proven numerics),
// LANE-MAJOR layout [sub][lane][e(+pad 34)]: read as u32 (2 bf16) with
// stride 68B -> 17 coprime 32 -> conflict-free (fixes round-4's 8-way
// conflicts, 5.3M -> ~1.3M). Bias is fed as the QK MFMA C-init (no VALU add).
// No K prefetch across the barrier (vmcnt(0) drain makes it worthless);
// V issued at top of iteration, consumed at PV; bias global loads for the
// next tile issued early, LDS-stored write-late before the single barrier.
// ---------------------------------------------------------------------------
__global__ __launch_bounds__(256, 3) void attn_kernel(const unsigned short* __restrict__ qg,
                                                      const unsigned short* __restrict__ kg,
                                                      const unsigned short* __restrict__ vg,
                                                      const float* __restrict__ bias,
                                                      unsigned short* __restrict__ ao) {
    const int i0   = blockIdx.x * 32;   // 32 q-rows per block (2 sub-tiles)
    const int h    = blockIdx.y;
    const int t    = threadIdx.x;
    const int b    = t >> 6;            // wave index = batch index (BB==4)
    const int lane = t & 63;
    const int l15  = lane & 15;
    const int quad = lane >> 4;

    // [dbuf][sub][lane][elem(+pad to 34)] bf16: elem e = 4*jj + r
    __shared__ unsigned short bias_l[2][2][64][34];   // 17408 B
    __shared__ unsigned short ps[BB][16][136];        // 17408 B

    const size_t bh = (size_t)b * NH + h;
    const unsigned short* qp = qg + bh * NN * DH;
    const unsigned short* kp = kg + bh * NN * DH;
    const unsigned short* vp = vg + bh * DH * NN;

    short8 qf0 = *(const short8*)(qp + (size_t)(i0 + l15) * DH + quad * 8);
    short8 qf1 = *(const short8*)(qp + (size_t)(i0 + 16 + l15) * DH + quad * 8);

    float4v oa00 = {0.f,0.f,0.f,0.f}, oa01 = {0.f,0.f,0.f,0.f};   // sub 0: d 0-15, 16-31
    float4v oa10 = {0.f,0.f,0.f,0.f}, oa11 = {0.f,0.f,0.f,0.f};   // sub 1
    float l_r[2][4] = {{0.f,0.f,0.f,0.f},{0.f,0.f,0.f,0.f}};

    // ---- bias staging map: thread covers rows {2*a2, 2*a2+1}, cols scol..+7
    // of the 32x128 tile. Row pair packs into one u32 (two bf16, adjacent e).
    const int a2    = t >> 4;                 // 0..15 -> rows 2a2, 2a2+1
    const int scol  = (t & 15) * 8;           // 0..120
    const int sub_s = a2 >> 3;                // rows 0-15 -> sub0, 16-31 -> sub1
    const int ln_b  = ((a2 & 7) >> 1) * 16 + (scol & 15);  // lane base for k'=scol
    const int e_b   = 4 * (scol >> 4) + 2 * (a2 & 1);      // elem (even), const over i
    const float* brow0 = bias + ((size_t)h * NN + i0 + 2 * a2) * NN;
    const float* brow1 = brow0 + NN;

#define BIAS_STAGE(BUF, JT)                                                        \
{                                                                                  \
    float4 x0 = *(const float4*)(brow0 + (JT) + scol);                             \
    float4 x1 = *(const float4*)(brow0 + (JT) + scol + 4);                         \
    float4 y0 = *(const float4*)(brow1 + (JT) + scol);                             \
    float4 y1 = *(const float4*)(brow1 + (JT) + scol + 4);                         \
    _Pragma("unroll")                                                              \
    for (int i = 0; i < 4; ++i) {                                                  \
        float xe0 = ((const float*)&x0)[i] * LOG2E, ye0 = ((const float*)&y0)[i] * LOG2E; \
        float xe1 = ((const float*)&x1)[i] * LOG2E, ye1 = ((const float*)&y1)[i] * LOG2E; \
        uint32_t p0 = (uint32_t)f2bf(xe0) | ((uint32_t)f2bf(ye0) << 16);           \
        uint32_t p1 = (uint32_t)f2bf(xe1) | ((uint32_t)f2bf(ye1) << 16);           \
        *(uint32_t*)&bias_l[BUF][sub_s][ln_b + i][e_b]     = p0;                   \
        *(uint32_t*)&bias_l[BUF][sub_s][ln_b + 4 + i][e_b] = p1;                   \
    }                                                                              \
}

    // prologue: stage bias tile 0
    BIAS_STAGE(0, 0)
    __syncthreads();

    int cur = 0;
    for (int jt = 0; jt < NN; jt += 128) {
        const int jtn = jt + 128;
        const bool have = (jtn < NN);          // uniform across block

        // V for THIS tile: issued first, consumed last (PV)
        short8 vv[8];
        #pragma unroll
        for (int cc = 0; cc < 4; ++cc) {
            vv[2*cc]   = *(const short8*)(vp + (size_t)l15 * NN        + jt + cc*32 + quad*8);
            vv[2*cc+1] = *(const short8*)(vp + (size_t)(l15+16) * NN   + jt + cc*32 + quad*8);
        }
        // K for THIS tile (L2-warm; covered by bias LDS reads + TLP)
        short8 kf[8];
        #pragma unroll
        for (int jj = 0; jj < 8; ++jj)
            kf[jj] = *(const short8*)(kp + (size_t)(jt + jj*16 + l15) * DH + quad*8);
        // bias global loads for NEXT tile (write-late at bottom)
        float4 nx0, nx1, ny0, ny1;
        if (have) {
            nx0 = *(const float4*)(brow0 + jtn + scol);
            nx1 = *(const float4*)(brow0 + jtn + scol + 4);
            ny0 = *(const float4*)(brow1 + jtn + scol);
            ny1 = *(const float4*)(brow1 + jtn + scol + 4);
        }

        // ---- two q-sub-tiles against the same K/V tile ----
        #pragma unroll
        for (int sub = 0; sub < 2; ++sub) {
            const short8 qf = sub ? qf1 : qf0;
            // S = Q K^T with bias as C-init (q pre-scaled by SCALE*LOG2E)
            float4v s[8];
            #pragma unroll
            for (int jj = 0; jj < 8; ++jj) {
                uint32_t u0 = *(const uint32_t*)&bias_l[cur][sub][lane][4*jj];
                uint32_t u1 = *(const uint32_t*)&bias_l[cur][sub][lane][4*jj + 2];
                float4v ci = { bits2f(u0 << 16), bits2f(u0 & 0xffff0000u),
                               bits2f(u1 << 16), bits2f(u1 & 0xffff0000u) };
                s[jj] = __builtin_amdgcn_mfma_f32_16x16x32_bf16(qf, kf[jj], ci, 0, 0, 0);
            }
            // p = exp2(s); pack pairs to bf16 (RNE); per-lane row partial sums
            #pragma unroll
            for (int r = 0; r < 4; ++r) {
                const int row = quad * 4 + r;
                float pv_[8];
                #pragma unroll
                for (int jj = 0; jj < 8; ++jj) { pv_[jj] = exp2f(s[jj][r]); l_r[sub][r] += pv_[jj]; }
                #pragma unroll
                for (int jp = 0; jp < 4; ++jp) {
                    uint32_t pk;
                    asm("v_cvt_pk_bf16_f32 %0, %1, %2" : "=v"(pk) : "v"(pv_[2*jp]), "v"(pv_[2*jp+1]));
                    ps[b][row][(2*jp)   * 16 + l15] = (unsigned short)pk;
                    ps[b][row][(2*jp+1) * 16 + l15] = (unsigned short)(pk >> 16);
                }
            }
            // O += P x V (ps wave-private: same-wave DS ordering, no barrier)
            #pragma unroll
            for (int cc = 0; cc < 4; ++cc) {
                short8 pa = *(const short8*)&ps[b][l15][cc * 32 + quad * 8];
                if (sub == 0) {
                    oa00 = __builtin_amdgcn_mfma_f32_16x16x32_bf16(pa, vv[2*cc],   oa00, 0, 0, 0);
                    oa01 = __builtin_amdgcn_mfma_f32_16x16x32_bf16(pa, vv[2*cc+1], oa01, 0, 0, 0);
                } else {
                    oa10 = __builtin_amdgcn_mfma_f32_16x16x32_bf16(pa, vv[2*cc],   oa10, 0, 0, 0);
                    oa11 = __builtin_amdgcn_mfma_f32_16x16x32_bf16(pa, vv[2*cc+1], oa11, 0, 0, 0);
                }
            }
        }

        // write-late: next bias tile into the other buffer, then the barrier
        if (have) {
            const int nxt = cur ^ 1;
            #pragma unroll
            for (int i = 0; i < 4; ++i) {
                float xe0 = ((const float*)&nx0)[i] * LOG2E, ye0 = ((const float*)&ny0)[i] * LOG2E;
                float xe1 = ((const float*)&nx1)[i] * LOG2E, ye1 = ((const float*)&ny1)[i] * LOG2E;
                uint32_t p0 = (uint32_t)f2bf(xe0) | ((uint32_t)f2bf(ye0) << 16);
                uint32_t p1 = (uint32_t)f2bf(xe1) | ((uint32_t)f2bf(ye1) << 16);
                *(uint32_t*)&bias_l[nxt][sub_s][ln_b + i][e_b]     = p0;
                *(uint32_t*)&bias_l[nxt][sub_s][ln_b + 4 + i][e_b] = p1;
            }
        }
        __syncthreads();
        cur ^= 1;
    }
#undef BIAS_STAGE

    // row-sum reduction across the 16 l15 lanes (stays within quad group)
    #pragma unroll
    for (int sub = 0; sub < 2; ++sub)
        #pragma unroll
        for (int r = 0; r < 4; ++r) {
            #pragma unroll
            for (int off = 1; off < 16; off <<= 1)
                l_r[sub][r] += __shfl_xor(l_r[sub][r], off, 64);
        }

    // epilogue: normalize, write bf16 to ao[b][i][h*32+d]
    unsigned short* aop = ao + ((size_t)b * NN + i0) * HID + h * DH;
    #pragma unroll
    for (int r = 0; r < 4; ++r) {
        const int row0 = quad * 4 + r;
        const float inv0 = 1.0f / l_r[0][r];
        const float inv1 = 1.0f / l_r[1][r];
        aop[(size_t)row0 * HID + l15]             = f2bf(oa00[r] * inv0);
        aop[(size_t)row0 * HID + 16 + l15]        = f2bf(oa01[r] * inv0);
        aop[(size_t)(row0 + 16) * HID + l15]      = f2bf(oa10[r] * inv1);
        aop[(size_t)(row0 + 16) * HID + 16 + l15] = f2bf(oa11[r] * inv1);
    }
}

// ---------------------------------------------------------------------------
// K3: out projection, bf16 MFMA.
// out[b][o][n] = sum_c w_out[o][c] * ao[b][n][c] + b_out[o]
// ---------------------------------------------------------------------------
__global__ __launch_bounds__(256) void out_proj(const unsigned short* __restrict__ wob,
                                                const unsigned short* __restrict__ aob,
                                                const float* __restrict__ bout,
                                                float* __restrict__ out) {
    const int n0 = blockIdx.x * 64;
    const int o0 = blockIdx.y * 64;
    const int b  = blockIdx.z;
    const int t = threadIdx.x;
    const int w = t >> 6, lane = t & 63, l15 = lane & 15, quad = lane >> 4;
    const int orow = o0 + w * 16;

    float4v acc[4] = {{0.f,0.f,0.f,0.f},{0.f,0.f,0.f,0.f},
                      {0.f,0.f,0.f,0.f},{0.f,0.f,0.f,0.f}};
    const unsigned short* ap = aob + ((size_t)b * NN + n0) * HID;
    #pragma unroll
    for (int c0 = 0; c0 < HID; c0 += 32) {
        short8 af = *(const short8*)(wob + (size_t)(orow + l15) * HID + c0 + quad * 8);
        #pragma unroll
        for (int jj = 0; jj < 4; ++jj) {
            short8 bf = *(const short8*)(ap + (size_t)(jj * 16 + l15) * HID + c0 + quad * 8);
            acc[jj] = __builtin_amdgcn_mfma_f32_16x16x32_bf16(af, bf, acc[jj], 0, 0, 0);
        }
    }
    float* op = out + (size_t)b * HID * NN;
    #pragma unroll
    for (int r = 0; r < 4; ++r) {
        const int o = orow + quad * 4 + r;
        const float bv = bout[o];
        #pragma unroll
        for (int jj = 0; jj < 4; ++jj)
            op[(size_t)o * NN + n0 + jj * 16 + l15] = acc[jj][r] + bv;
    }
}

// ---------------------------------------------------------------------------
extern "C" void kernel_launch(void* const* d_in, const int* in_sizes, int n_in,
                              void* d_out, int out_size, void* d_ws, size_t ws_size,
                              hipStream_t stream) {
    const float* x        = (const float*)d_in[0];  // [4][256][2304]
    const float* pos_bias = (const float*)d_in[1];  // [8][2304][2304]
    const float* w_qkv    = (const float*)d_in[2];  // [768][256]
    const float* w_out    = (const float*)d_in[3];  // [256][256]
    const float* b_out    = (const float*)d_in[4];  // [256]
    float* out = (float*)d_out;                     // [4][256][2304]

    // workspace carve-up (256B-aligned); total ~24.5 MB (proven-safe size)
    char* ws = (char*)d_ws;
    unsigned short* q   = (unsigned short*)(ws);                      //  4,718,592
    unsigned short* k   = (unsigned short*)(ws + 4718592);            //  4,718,592
    unsigned short* v   = (unsigned short*)(ws + 9437184);            //  4,718,592
    unsigned short* ao  = (unsigned short*)(ws + 14155776);           //  4,718,592
    unsigned short* wob = (unsigned short*)(ws + 18874368);           //    131,072
    unsigned short* whi = (unsigned short*)(ws + 19005440);           //    393,216
    unsigned short* wlo = (unsigned short*)(ws + 19398656);           //    393,216
    unsigned short* xT  = (unsigned short*)(ws + 19791872);           //  4,718,592

    prep_kernel<<<3072, 256, 0, stream>>>(x, w_qkv, w_out, xT, whi, wlo, wob);
    qkv_gemm_bf16<<<dim3(12, NN / 64, BB), 256, 0, stream>>>(xT, whi, wlo, q, k, v);
    attn_kernel<<<dim3(NN / 32, NH), 256, 0, stream>>>(q, k, v, pos_bias, ao);
    out_proj<<<dim3(NN / 64, HID / 64, BB), 256, 0, stream>>>(wob, ao, b_out, out);
}

// Round 6
// 430.815 us; speedup vs baseline: 1.1451x; 1.1451x over previous
//
#include <hip/hip_runtime.h>
#include <stdint.h>
#include <stddef.h>

// Problem constants
#define BB 4
#define CC 256
#define NH 8
#define DH 32
#define NN 2304      // 48*48
#define O3 768
#define HID 256
#define QK_SCALE 0.17677669529663687f  // 32^-0.5
#define LOG2E 1.44269504f

typedef __attribute__((ext_vector_type(8))) short short8;
typedef __attribute__((ext_vector_type(4))) float float4v;

__device__ __forceinline__ unsigned short f2bf(float f) {
    union { float f; uint32_t u; } v; v.f = f;
    uint32_t u = v.u;
    return (unsigned short)((u + 0x7FFFu + ((u >> 16) & 1u)) >> 16);   // RNE
}
__device__ __forceinline__ float bf2f(unsigned short s) {
    union { uint32_t u; float f; } v; v.u = ((uint32_t)s) << 16;
    return v.f;
}
__device__ __forceinline__ float bits2f(uint32_t u) {
    union { uint32_t u; float f; } v; v.u = u;
    return v.f;
}

// ---------------------------------------------------------------------------
// K0: prep = transpose-cast x -> xT bf16  (blocks 0..2303)
//          + cast w_qkv hi/lo, w_out      (blocks 2304..3071)
// ---------------------------------------------------------------------------
__global__ __launch_bounds__(256) void prep_kernel(const float* __restrict__ x,
                                                   const float* __restrict__ wqkv,
                                                   const float* __restrict__ wout,
                                                   unsigned short* __restrict__ xT,
                                                   unsigned short* __restrict__ whi,
                                                   unsigned short* __restrict__ wlo,
                                                   unsigned short* __restrict__ wob) {
    const int bid = blockIdx.x;
    const int t = threadIdx.x;
    if (bid < 2304) {      // transpose 32x32 tile of x
        const int n0 = (bid % 72) * 32, c0 = ((bid / 72) % 8) * 32, b = bid / 576;
        __shared__ float ls[32][33];
        {
            int c = t >> 3, nc = (t & 7) * 4;
            float4 v4 = *(const float4*)(x + ((size_t)b * CC + c0 + c) * NN + n0 + nc);
            ls[c][nc] = v4.x; ls[c][nc + 1] = v4.y; ls[c][nc + 2] = v4.z; ls[c][nc + 3] = v4.w;
        }
        __syncthreads();
        {
            int n = t >> 3, cl = (t & 7) * 4;
            uint32_t p0 = (uint32_t)f2bf(ls[cl + 0][n]) | ((uint32_t)f2bf(ls[cl + 1][n]) << 16);
            uint32_t p1 = (uint32_t)f2bf(ls[cl + 2][n]) | ((uint32_t)f2bf(ls[cl + 3][n]) << 16);
            uint32_t* dst = (uint32_t*)(xT + ((size_t)b * NN + n0 + n) * CC + c0 + cl);
            dst[0] = p0; dst[1] = p1;
        }
    } else {               // weight casts
        int i = (bid - 2304) * 256 + t;
        float wv = wqkv[i];
        unsigned short hi = f2bf(wv);
        whi[i] = hi;
        wlo[i] = f2bf(wv - bf2f(hi));
        if (i < HID * HID) wob[i] = f2bf(wout[i]);
    }
}

// ---------------------------------------------------------------------------
// K1: fused QKV projection, bf16 MFMA, writes q/k/v directly in final layouts.
//   q,k bf16 [b][h][n][32] (q scaled by QK_SCALE*LOG2E), v bf16 [b][h][32][n]
// ---------------------------------------------------------------------------
__global__ __launch_bounds__(256) void qkv_gemm_bf16(const unsigned short* __restrict__ xT,
                                                     const unsigned short* __restrict__ whi,
                                                     const unsigned short* __restrict__ wlo,
                                                     unsigned short* __restrict__ q,
                                                     unsigned short* __restrict__ k,
                                                     unsigned short* __restrict__ v) {
    const int og = blockIdx.x;
    const int n0 = blockIdx.y * 64;
    const int b  = blockIdx.z;
    const int t = threadIdx.x;
    const int w = t >> 6, lane = t & 63, l15 = lane & 15, quad = lane >> 4;
    const unsigned short* xb = xT + (size_t)b * NN * CC;

    float4v acc[4] = {{0.f,0.f,0.f,0.f},{0.f,0.f,0.f,0.f},
                      {0.f,0.f,0.f,0.f},{0.f,0.f,0.f,0.f}};

    if (og < 8) {   // ---- qk mode: A = xT rows n, B = w rows o ----
        const int o0 = og * 64;
        const unsigned short* ap = xb + (size_t)(n0 + w * 16 + l15) * CC + quad * 8;
        #pragma unroll
        for (int c0 = 0; c0 < CC; c0 += 32) {
            short8 af = *(const short8*)(ap + c0);
            #pragma unroll
            for (int jj = 0; jj < 4; ++jj) {
                const size_t wo = (size_t)(o0 + jj * 16 + l15) * CC + c0 + quad * 8;
                short8 bh = *(const short8*)(whi + wo);
                short8 bl = *(const short8*)(wlo + wo);
                acc[jj] = __builtin_amdgcn_mfma_f32_16x16x32_bf16(af, bh, acc[jj], 0, 0, 0);
                acc[jj] = __builtin_amdgcn_mfma_f32_16x16x32_bf16(af, bl, acc[jj], 0, 0, 0);
            }
        }
        #pragma unroll
        for (int jj = 0; jj < 4; ++jj) {
            const int o = o0 + jj * 16 + l15;
            const int which = o >> 8;            // 0=q 1=k
            const int h = (o >> 5) & 7, d = o & 31;
            unsigned short* dst = which ? k : q;
            const float sc = which ? 1.0f : QK_SCALE * LOG2E;
            #pragma unroll
            for (int r = 0; r < 4; ++r) {
                const int n = n0 + w * 16 + quad * 4 + r;
                dst[(((size_t)b * NH + h) * NN + n) * DH + d] = f2bf(acc[jj][r] * sc);
            }
        }
    } else {        // ---- v mode: A = w rows o, B = xT rows n ----
        const int o0 = 512 + (og - 8) * 64;
        const size_t wr = (size_t)(o0 + w * 16 + l15) * CC + quad * 8;
        #pragma unroll
        for (int c0 = 0; c0 < CC; c0 += 32) {
            short8 ah = *(const short8*)(whi + wr + c0);
            short8 al = *(const short8*)(wlo + wr + c0);
            #pragma unroll
            for (int jj = 0; jj < 4; ++jj) {
                short8 bf = *(const short8*)(xb + (size_t)(n0 + jj * 16 + l15) * CC + c0 + quad * 8);
                acc[jj] = __builtin_amdgcn_mfma_f32_16x16x32_bf16(ah, bf, acc[jj], 0, 0, 0);
                acc[jj] = __builtin_amdgcn_mfma_f32_16x16x32_bf16(al, bf, acc[jj], 0, 0, 0);
            }
        }
        #pragma unroll
        for (int r = 0; r < 4; ++r) {
            const int o = o0 + w * 16 + quad * 4 + r;
            const int h = (o >> 5) & 7, d = o & 31;
            #pragma unroll
            for (int jj = 0; jj < 4; ++jj) {
                const int n = n0 + jj * 16 + l15;
                v[(((size_t)b * NH + h) * DH + d) * NN + n] = f2bf(acc[jj][r]);
            }
        }
    }
}

// ---------------------------------------------------------------------------
// K2: fused attention v6 = v5 body with the VGPR cap REMOVED (the round-5
// launch_bounds(256,3) forced VGPR=84 < the ~150 live set -> per-iteration
// scratch spills: WRITE_SIZE 5.4->194 MB, dur 178->240 us. Single-variable
// fix; everything else identical to v5).
// QBLK=32: each wave computes TWO 16-row q-sub-tiles against the SAME K/V
// tile -> K/V L2 traffic halved, 16 MFMAs per 16 loads. Grid (72, 8) = 576
// blocks of 4 waves (wave=batch). Bias shared across the 4 batch-waves in
// LDS as bf16, lane-major [sub][lane][34]: u32 reads, stride 68B, 17 coprime
// 32 -> conflict-free (round-5 verified: conflicts 5.3M -> 2.0M). Bias fed
// as QK MFMA C-init. V issued at top of iteration, consumed at PV; bias
// global loads for next tile issued early, LDS-stored write-late.
// ---------------------------------------------------------------------------
__global__ __launch_bounds__(256) void attn_kernel(const unsigned short* __restrict__ qg,
                                                   const unsigned short* __restrict__ kg,
                                                   const unsigned short* __restrict__ vg,
                                                   const float* __restrict__ bias,
                                                   unsigned short* __restrict__ ao) {
    const int i0   = blockIdx.x * 32;   // 32 q-rows per block (2 sub-tiles)
    const int h    = blockIdx.y;
    const int t    = threadIdx.x;
    const int b    = t >> 6;            // wave index = batch index (BB==4)
    const int lane = t & 63;
    const int l15  = lane & 15;
    const int quad = lane >> 4;

    // [dbuf][sub][lane][elem(+pad to 34)] bf16: elem e = 4*jj + r
    __shared__ unsigned short bias_l[2][2][64][34];   // 17408 B
    __shared__ unsigned short ps[BB][16][136];        // 17408 B

    const size_t bh = (size_t)b * NH + h;
    const unsigned short* qp = qg + bh * NN * DH;
    const unsigned short* kp = kg + bh * NN * DH;
    const unsigned short* vp = vg + bh * DH * NN;

    short8 qf0 = *(const short8*)(qp + (size_t)(i0 + l15) * DH + quad * 8);
    short8 qf1 = *(const short8*)(qp + (size_t)(i0 + 16 + l15) * DH + quad * 8);

    float4v oa00 = {0.f,0.f,0.f,0.f}, oa01 = {0.f,0.f,0.f,0.f};   // sub 0: d 0-15, 16-31
    float4v oa10 = {0.f,0.f,0.f,0.f}, oa11 = {0.f,0.f,0.f,0.f};   // sub 1
    float l_r[2][4] = {{0.f,0.f,0.f,0.f},{0.f,0.f,0.f,0.f}};

    // ---- bias staging map: thread covers rows {2*a2, 2*a2+1}, cols scol..+7
    // of the 32x128 tile. Row pair packs into one u32 (two bf16, adjacent e).
    const int a2    = t >> 4;                 // 0..15 -> rows 2a2, 2a2+1
    const int scol  = (t & 15) * 8;           // 0..120
    const int sub_s = a2 >> 3;                // rows 0-15 -> sub0, 16-31 -> sub1
    const int ln_b  = ((a2 & 7) >> 1) * 16 + (scol & 15);  // lane base for k'=scol
    const int e_b   = 4 * (scol >> 4) + 2 * (a2 & 1);      // elem (even), const over i
    const float* brow0 = bias + ((size_t)h * NN + i0 + 2 * a2) * NN;
    const float* brow1 = brow0 + NN;

#define BIAS_STAGE(BUF, JT)                                                        \
{                                                                                  \
    float4 x0 = *(const float4*)(brow0 + (JT) + scol);                             \
    float4 x1 = *(const float4*)(brow0 + (JT) + scol + 4);                         \
    float4 y0 = *(const float4*)(brow1 + (JT) + scol);                             \
    float4 y1 = *(const float4*)(brow1 + (JT) + scol + 4);                         \
    _Pragma("unroll")                                                              \
    for (int i = 0; i < 4; ++i) {                                                  \
        float xe0 = ((const float*)&x0)[i] * LOG2E, ye0 = ((const float*)&y0)[i] * LOG2E; \
        float xe1 = ((const float*)&x1)[i] * LOG2E, ye1 = ((const float*)&y1)[i] * LOG2E; \
        uint32_t p0 = (uint32_t)f2bf(xe0) | ((uint32_t)f2bf(ye0) << 16);           \
        uint32_t p1 = (uint32_t)f2bf(xe1) | ((uint32_t)f2bf(ye1) << 16);           \
        *(uint32_t*)&bias_l[BUF][sub_s][ln_b + i][e_b]     = p0;                   \
        *(uint32_t*)&bias_l[BUF][sub_s][ln_b + 4 + i][e_b] = p1;                   \
    }                                                                              \
}

    // prologue: stage bias tile 0
    BIAS_STAGE(0, 0)
    __syncthreads();

    int cur = 0;
    for (int jt = 0; jt < NN; jt += 128) {
        const int jtn = jt + 128;
        const bool have = (jtn < NN);          // uniform across block

        // V for THIS tile: issued first, consumed last (PV)
        short8 vv[8];
        #pragma unroll
        for (int cc = 0; cc < 4; ++cc) {
            vv[2*cc]   = *(const short8*)(vp + (size_t)l15 * NN        + jt + cc*32 + quad*8);
            vv[2*cc+1] = *(const short8*)(vp + (size_t)(l15+16) * NN   + jt + cc*32 + quad*8);
        }
        // K for THIS tile (L2-warm; covered by bias LDS reads + TLP)
        short8 kf[8];
        #pragma unroll
        for (int jj = 0; jj < 8; ++jj)
            kf[jj] = *(const short8*)(kp + (size_t)(jt + jj*16 + l15) * DH + quad*8);
        // bias global loads for NEXT tile (write-late at bottom)
        float4 nx0, nx1, ny0, ny1;
        if (have) {
            nx0 = *(const float4*)(brow0 + jtn + scol);
            nx1 = *(const float4*)(brow0 + jtn + scol + 4);
            ny0 = *(const float4*)(brow1 + jtn + scol);
            ny1 = *(const float4*)(brow1 + jtn + scol + 4);
        }

        // ---- two q-sub-tiles against the same K/V tile ----
        #pragma unroll
        for (int sub = 0; sub < 2; ++sub) {
            const short8 qf = sub ? qf1 : qf0;
            // S = Q K^T with bias as C-init (q pre-scaled by SCALE*LOG2E)
            float4v s[8];
            #pragma unroll
            for (int jj = 0; jj < 8; ++jj) {
                uint32_t u0 = *(const uint32_t*)&bias_l[cur][sub][lane][4*jj];
                uint32_t u1 = *(const uint32_t*)&bias_l[cur][sub][lane][4*jj + 2];
                float4v ci = { bits2f(u0 << 16), bits2f(u0 & 0xffff0000u),
                               bits2f(u1 << 16), bits2f(u1 & 0xffff0000u) };
                s[jj] = __builtin_amdgcn_mfma_f32_16x16x32_bf16(qf, kf[jj], ci, 0, 0, 0);
            }
            // p = exp2(s); pack pairs to bf16 (RNE); per-lane row partial sums
            #pragma unroll
            for (int r = 0; r < 4; ++r) {
                const int row = quad * 4 + r;
                float pv_[8];
                #pragma unroll
                for (int jj = 0; jj < 8; ++jj) { pv_[jj] = exp2f(s[jj][r]); l_r[sub][r] += pv_[jj]; }
                #pragma unroll
                for (int jp = 0; jp < 4; ++jp) {
                    uint32_t pk;
                    asm("v_cvt_pk_bf16_f32 %0, %1, %2" : "=v"(pk) : "v"(pv_[2*jp]), "v"(pv_[2*jp+1]));
                    ps[b][row][(2*jp)   * 16 + l15] = (unsigned short)pk;
                    ps[b][row][(2*jp+1) * 16 + l15] = (unsigned short)(pk >> 16);
                }
            }
            // O += P x V (ps wave-private: same-wave DS ordering, no barrier)
            #pragma unroll
            for (int cc = 0; cc < 4; ++cc) {
                short8 pa = *(const short8*)&ps[b][l15][cc * 32 + quad * 8];
                if (sub == 0) {
                    oa00 = __builtin_amdgcn_mfma_f32_16x16x32_bf16(pa, vv[2*cc],   oa00, 0, 0, 0);
                    oa01 = __builtin_amdgcn_mfma_f32_16x16x32_bf16(pa, vv[2*cc+1], oa01, 0, 0, 0);
                } else {
                    oa10 = __builtin_amdgcn_mfma_f32_16x16x32_bf16(pa, vv[2*cc],   oa10, 0, 0, 0);
                    oa11 = __builtin_amdgcn_mfma_f32_16x16x32_bf16(pa, vv[2*cc+1], oa11, 0, 0, 0);
                }
            }
        }

        // write-late: next bias tile into the other buffer, then the barrier
        if (have) {
            const int nxt = cur ^ 1;
            #pragma unroll
            for (int i = 0; i < 4; ++i) {
                float xe0 = ((const float*)&nx0)[i] * LOG2E, ye0 = ((const float*)&ny0)[i] * LOG2E;
                float xe1 = ((const float*)&nx1)[i] * LOG2E, ye1 = ((const float*)&ny1)[i] * LOG2E;
                uint32_t p0 = (uint32_t)f2bf(xe0) | ((uint32_t)f2bf(ye0) << 16);
                uint32_t p1 = (uint32_t)f2bf(xe1) | ((uint32_t)f2bf(ye1) << 16);
                *(uint32_t*)&bias_l[nxt][sub_s][ln_b + i][e_b]     = p0;
                *(uint32_t*)&bias_l[nxt][sub_s][ln_b + 4 + i][e_b] = p1;
            }
        }
        __syncthreads();
        cur ^= 1;
    }
#undef BIAS_STAGE

    // row-sum reduction across the 16 l15 lanes (stays within quad group)
    #pragma unroll
    for (int sub = 0; sub < 2; ++sub)
        #pragma unroll
        for (int r = 0; r < 4; ++r) {
            #pragma unroll
            for (int off = 1; off < 16; off <<= 1)
                l_r[sub][r] += __shfl_xor(l_r[sub][r], off, 64);
        }

    // epilogue: normalize, write bf16 to ao[b][i][h*32+d]
    unsigned short* aop = ao + ((size_t)b * NN + i0) * HID + h * DH;
    #pragma unroll
    for (int r = 0; r < 4; ++r) {
        const int row0 = quad * 4 + r;
        const float inv0 = 1.0f / l_r[0][r];
        const float inv1 = 1.0f / l_r[1][r];
        aop[(size_t)row0 * HID + l15]             = f2bf(oa00[r] * inv0);
        aop[(size_t)row0 * HID + 16 + l15]        = f2bf(oa01[r] * inv0);
        aop[(size_t)(row0 + 16) * HID + l15]      = f2bf(oa10[r] * inv1);
        aop[(size_t)(row0 + 16) * HID + 16 + l15] = f2bf(oa11[r] * inv1);
    }
}

// ---------------------------------------------------------------------------
// K3: out projection, bf16 MFMA.
// out[b][o][n] = sum_c w_out[o][c] * ao[b][n][c] + b_out[o]
// ---------------------------------------------------------------------------
__global__ __launch_bounds__(256) void out_proj(const unsigned short* __restrict__ wob,
                                                const unsigned short* __restrict__ aob,
                                                const float* __restrict__ bout,
                                                float* __restrict__ out) {
    const int n0 = blockIdx.x * 64;
    const int o0 = blockIdx.y * 64;
    const int b  = blockIdx.z;
    const int t = threadIdx.x;
    const int w = t >> 6, lane = t & 63, l15 = lane & 15, quad = lane >> 4;
    const int orow = o0 + w * 16;

    float4v acc[4] = {{0.f,0.f,0.f,0.f},{0.f,0.f,0.f,0.f},
                      {0.f,0.f,0.f,0.f},{0.f,0.f,0.f,0.f}};
    const unsigned short* ap = aob + ((size_t)b * NN + n0) * HID;
    #pragma unroll
    for (int c0 = 0; c0 < HID; c0 += 32) {
        short8 af = *(const short8*)(wob + (size_t)(orow + l15) * HID + c0 + quad * 8);
        #pragma unroll
        for (int jj = 0; jj < 4; ++jj) {
            short8 bf = *(const short8*)(ap + (size_t)(jj * 16 + l15) * HID + c0 + quad * 8);
            acc[jj] = __builtin_amdgcn_mfma_f32_16x16x32_bf16(af, bf, acc[jj], 0, 0, 0);
        }
    }
    float* op = out + (size_t)b * HID * NN;
    #pragma unroll
    for (int r = 0; r < 4; ++r) {
        const int o = orow + quad * 4 + r;
        const float bv = bout[o];
        #pragma unroll
        for (int jj = 0; jj < 4; ++jj)
            op[(size_t)o * NN + n0 + jj * 16 + l15] = acc[jj][r] + bv;
    }
}

// ---------------------------------------------------------------------------
extern "C" void kernel_launch(void* const* d_in, const int* in_sizes, int n_in,
                              void* d_out, int out_size, void* d_ws, size_t ws_size,
                              hipStream_t stream) {
    const float* x        = (const float*)d_in[0];  // [4][256][2304]
    const float* pos_bias = (const float*)d_in[1];  // [8][2304][2304]
    const float* w_qkv    = (const float*)d_in[2];  // [768][256]
    const float* w_out    = (const float*)d_in[3];  // [256][256]
    const float* b_out    = (const float*)d_in[4];  // [256]
    float* out = (float*)d_out;                     // [4][256][2304]

    // workspace carve-up (256B-aligned); total ~24.5 MB (proven-safe size)
    char* ws = (char*)d_ws;
    unsigned short* q   = (unsigned short*)(ws);                      //  4,718,592
    unsigned short* k   = (unsigned short*)(ws + 4718592);            //  4,718,592
    unsigned short* v   = (unsigned short*)(ws + 9437184);            //  4,718,592
    unsigned short* ao  = (unsigned short*)(ws + 14155776);           //  4,718,592
    unsigned short* wob = (unsigned short*)(ws + 18874368);           //    131,072
    unsigned short* whi = (unsigned short*)(ws + 19005440);           //    393,216
    unsigned short* wlo = (unsigned short*)(ws + 19398656);           //    393,216
    unsigned short* xT  = (unsigned short*)(ws + 19791872);           //  4,718,592

    prep_kernel<<<3072, 256, 0, stream>>>(x, w_qkv, w_out, xT, whi, wlo, wob);
    qkv_gemm_bf16<<<dim3(12, NN / 64, BB), 256, 0, stream>>>(xT, whi, wlo, q, k, v);
    attn_kernel<<<dim3(NN / 32, NH), 256, 0, stream>>>(q, k, v, pos_bias, ao);
    out_proj<<<dim3(NN / 64, HID / 64, BB), 256, 0, stream>>>(wob, ao, b_out, out);
}